// Round 1
// baseline (793.154 us; speedup 1.0000x reference)
//
#include <hip/hip_runtime.h>

#define L 1024
#define HALF 512
#define BLOCK 256

__device__ __forceinline__ float soft_thr(float c, float thr) {
    float a = fabsf(c);
    return (a >= thr) ? copysignf(a - thr, c) : 0.0f;
}

__global__ __launch_bounds__(BLOCK) void wavelet_denoise_kernel(
        const float* __restrict__ x, float* __restrict__ out) {
    constexpr float INV_SQRT2 = 0.70710678118654752f;
    // (float)sqrt(2.0*log(1024.0)) computed in double, rounded to f32 like reference
    constexpr float SQRT_2LOGL = 3.7232974111f;

    __shared__ float s_ca1[HALF];
    __shared__ float s_med[HALF];
    __shared__ float s_ca2[256];
    __shared__ float s_ca3[128];
    __shared__ float s_cd3[128];

    const int row = blockIdx.x;
    const int t = threadIdx.x;
    const long long base = (long long)row * L;

    // ---- load 4 consecutive elements (coalesced float4) ----
    const float4 v = ((const float4*)(x + base))[t];

    // ---- level 1 DWT: thread t owns pairs (2t, 2t+1) of ca1/cd1 ----
    float ca1a = (v.x + v.y) * INV_SQRT2;
    float cd1a = (v.x - v.y) * INV_SQRT2;
    float ca1b = (v.z + v.w) * INV_SQRT2;
    float cd1b = (v.z - v.w) * INV_SQRT2;
    s_ca1[2 * t]     = ca1a;
    s_ca1[2 * t + 1] = ca1b;
    s_med[2 * t]     = fabsf(cd1a);
    s_med[2 * t + 1] = fabsf(cd1b);
    __syncthreads();

    // ---- level 2: thread t owns ca2[t], cd2[t] ----
    float a0 = s_ca1[2 * t], a1 = s_ca1[2 * t + 1];
    float ca2 = (a0 + a1) * INV_SQRT2;
    float cd2 = (a0 - a1) * INV_SQRT2;   // stays in register; needed for reconstruction
    s_ca2[t] = ca2;
    __syncthreads();

    // ---- level 3: threads t<128 compute ca3[t], cd3[t] ----
    if (t < 128) {
        float b0 = s_ca2[2 * t], b1 = s_ca2[2 * t + 1];
        s_ca3[t] = (b0 + b1) * INV_SQRT2;
        s_cd3[t] = (b0 - b1) * INV_SQRT2;
    }

    // ---- exact median of 512 |cd1| values: bitonic sort in LDS ----
    for (int k = 2; k <= HALF; k <<= 1) {
        for (int j = k >> 1; j > 0; j >>= 1) {
            __syncthreads();
            #pragma unroll
            for (int pass = 0; pass < 2; ++pass) {
                int i = t + pass * BLOCK;
                int ixj = i ^ j;
                if (ixj > i) {
                    float vi = s_med[i], vj = s_med[ixj];
                    bool up = ((i & k) == 0);
                    if ((vi > vj) == up) { s_med[i] = vj; s_med[ixj] = vi; }
                }
            }
        }
    }
    __syncthreads();

    const float median = 0.5f * (s_med[255] + s_med[256]);
    const float sigma  = median / 0.6745f;
    const float lamda  = sigma * SQRT_2LOGL;
    const float thr1 = lamda;                  // / log2(2) == 1
    const float thr2 = lamda / 1.5849625007f;  // / log2(3)
    const float thr3 = lamda * 0.5f;           // / log2(4) == 2 (exact)

    // ---- reconstruction ----
    // level 3 inverse: ca2r[t] from ca3[t>>1], cd3[t>>1]
    float ca3v = s_ca3[t >> 1];
    float cd3v = soft_thr(s_cd3[t >> 1], thr3);
    float ca2r = ((t & 1) == 0) ? (ca3v + cd3v) * INV_SQRT2
                                : (ca3v - cd3v) * INV_SQRT2;
    // level 2 inverse: ca1r[2t], ca1r[2t+1]
    float cd2s = soft_thr(cd2, thr2);
    float ca1r0 = (ca2r + cd2s) * INV_SQRT2;
    float ca1r1 = (ca2r - cd2s) * INV_SQRT2;
    // level 1 inverse: out[4t .. 4t+3]
    float cd1s0 = soft_thr(cd1a, thr1);
    float cd1s1 = soft_thr(cd1b, thr1);
    float4 o;
    o.x = (ca1r0 + cd1s0) * INV_SQRT2;
    o.y = (ca1r0 - cd1s0) * INV_SQRT2;
    o.z = (ca1r1 + cd1s1) * INV_SQRT2;
    o.w = (ca1r1 - cd1s1) * INV_SQRT2;
    ((float4*)(out + base))[t] = o;
}

extern "C" void kernel_launch(void* const* d_in, const int* in_sizes, int n_in,
                              void* d_out, int out_size, void* d_ws, size_t ws_size,
                              hipStream_t stream) {
    const float* x = (const float*)d_in[0];
    float* out = (float*)d_out;
    const int rows = in_sizes[0] / L;   // 64*1024 = 65536
    wavelet_denoise_kernel<<<rows, BLOCK, 0, stream>>>(x, out);
}

// Round 2
// 442.042 us; speedup vs baseline: 1.7943x; 1.7943x over previous
//
#include <hip/hip_runtime.h>

#define L 1024
#define BLOCK 256   // 4 waves, 1 row per wave

__device__ __forceinline__ float soft_thr(float c, float thr) {
    float a = fabsf(c);
    return (a >= thr) ? copysignf(a - thr, c) : 0.0f;
}

__global__ __launch_bounds__(BLOCK) void wavelet_denoise_kernel(
        const float* __restrict__ x, float* __restrict__ out) {
    constexpr float IS2 = 0.70710678118654752f;
    constexpr float SQRT_2LOGL = 3.7232974111f;   // f32(sqrt(2*ln(1024)))

    const int lane = threadIdx.x & 63;
    const int wid  = threadIdx.x >> 6;
    const long long row = (long long)blockIdx.x * 4 + wid;
    const float* xr = x + row * L;
    float* orow = out + row * L;

    // ---- load: 4 coalesced float4 chunks; chunk j = elements (j*64+lane)*4 .. +3
    float4 in[4];
    #pragma unroll
    for (int j = 0; j < 4; ++j)
        in[j] = ((const float4*)xr)[j * 64 + lane];

    // ---- level 1 DWT: lane owns ca1/cd1 pair indices {128j + 2*lane, +1}
    float ca1[8], cd1[8];
    #pragma unroll
    for (int j = 0; j < 4; ++j) {
        ca1[2*j]   = (in[j].x + in[j].y) * IS2;
        cd1[2*j]   = (in[j].x - in[j].y) * IS2;
        ca1[2*j+1] = (in[j].z + in[j].w) * IS2;
        cd1[2*j+1] = (in[j].z - in[j].w) * IS2;
    }

    // ---- level 2: lane owns ca2/cd2 at index 64j + lane (local pairs)
    float ca2[4], cd2[4];
    #pragma unroll
    for (int j = 0; j < 4; ++j) {
        ca2[j] = (ca1[2*j] + ca1[2*j+1]) * IS2;
        cd2[j] = (ca1[2*j] - ca1[2*j+1]) * IS2;
    }

    // ---- level 3: adjacent-lane combine; even lane 2m holds ca3/cd3[32j + m]
    float ca3[4], cd3[4];
    #pragma unroll
    for (int j = 0; j < 4; ++j) {
        float o = __shfl_xor(ca2[j], 1);
        ca3[j] = (ca2[j] + o) * IS2;   // valid on even lanes (odd lanes: unused garbage)
        cd3[j] = (ca2[j] - o) * IS2;
    }

    // ---- exact median of 512 |cd1|: register-resident bitonic sort,
    //      element index i = lane*8 + r, ascending. j<8 stages are in-lane.
    float v[8];
    #pragma unroll
    for (int r = 0; r < 8; ++r) v[r] = fabsf(cd1[r]);

    const int i0 = lane << 3;
    #pragma unroll
    for (int k = 2; k <= 512; k <<= 1) {
        #pragma unroll
        for (int j = k >> 1; j > 0; j >>= 1) {
            if (j >= 8) {
                const int lmask = j >> 3;
                const bool keep_min = (((i0 & k) == 0) == ((lane & lmask) == 0));
                #pragma unroll
                for (int r = 0; r < 8; ++r) {
                    float o = __shfl_xor(v[r], lmask);
                    v[r] = keep_min ? fminf(v[r], o) : fmaxf(v[r], o);
                }
            } else {
                #pragma unroll
                for (int r = 0; r < 8; ++r) {
                    if ((r & j) == 0) {
                        const int p = r | j;
                        const bool up = (((i0 | r) & k) == 0);
                        float lo = fminf(v[r], v[p]);
                        float hi = fmaxf(v[r], v[p]);
                        v[r] = up ? lo : hi;
                        v[p] = up ? hi : lo;
                    }
                }
            }
        }
    }

    // sorted[255] = lane31.v[7], sorted[256] = lane32.v[0]
    const float m0 = __shfl(v[7], 31);
    const float m1 = __shfl(v[0], 32);
    const float median = 0.5f * (m0 + m1);
    const float lam  = (median / 0.6745f) * SQRT_2LOGL;
    const float thr1 = lam;                      // / log2(2)
    const float thr2 = lam / 1.5849625007f;      // / log2(3)
    const float thr3 = lam * 0.5f;               // / log2(4)

    // ---- reconstruction (all local / single shuffle per level-3 fetch)
    #pragma unroll
    for (int j = 0; j < 4; ++j) {
        // ca2r[64j+lane] needs ca3/cd3[32j + lane/2], held in lane (lane & ~1)
        float c3 = __shfl(ca3[j], lane & 62);
        float d3 = soft_thr(__shfl(cd3[j], lane & 62), thr3);
        float ca2r = ((lane & 1) == 0) ? (c3 + d3) * IS2 : (c3 - d3) * IS2;

        float d2 = soft_thr(cd2[j], thr2);
        float ca1r0 = (ca2r + d2) * IS2;
        float ca1r1 = (ca2r - d2) * IS2;

        float d10 = soft_thr(cd1[2*j],   thr1);
        float d11 = soft_thr(cd1[2*j+1], thr1);
        float4 o;
        o.x = (ca1r0 + d10) * IS2;
        o.y = (ca1r0 - d10) * IS2;
        o.z = (ca1r1 + d11) * IS2;
        o.w = (ca1r1 - d11) * IS2;
        ((float4*)orow)[j * 64 + lane] = o;
    }
}

extern "C" void kernel_launch(void* const* d_in, const int* in_sizes, int n_in,
                              void* d_out, int out_size, void* d_ws, size_t ws_size,
                              hipStream_t stream) {
    const float* x = (const float*)d_in[0];
    float* out = (float*)d_out;
    const int rows = in_sizes[0] / L;           // 65536
    wavelet_denoise_kernel<<<rows / 4, BLOCK, 0, stream>>>(x, out);
}